// Round 10
// baseline (80.973 us; speedup 1.0000x reference)
//
#include <hip/hip_runtime.h>
#include <hip/hip_bf16.h>

typedef float f32x4 __attribute__((ext_vector_type(4)));

#define ZD      128      // feature dim (= bytes per fp8 row)
#define BT      128      // block tile (128x128, 64x64 per wave)
#define D2_CUT  60.0f    // exact-path cutoff: exp(-30)~9e-14
#define D2_TRIG 70.0f    // trigger: fp8 dot err <= ~+-3 on d2 => skip implies
                         // true d2 >= 70-6 > D2_CUT (12-sigma data margin)

// async global->LDS DMA, 16B per lane; LDS dest = wave-uniform base + lane*16
__device__ __forceinline__ void async_copy16(const unsigned char* g,
                                             unsigned char* l) {
    __builtin_amdgcn_global_load_lds(
        (const __attribute__((address_space(1))) unsigned int*)g,
        (__attribute__((address_space(3))) unsigned int*)l,
        16, 0, 0);
}

// ---------------------------------------------------------------------------
// Kernel A: 256 blocks x 32 rows. ||z_i||^2 (fp32 exact), per-32-row min,
// z -> fp8 e4m3 (HW cvt_pk). Block 0 extras: wave 2 = class counts over all
// s + analytic diagonal + out[0] = diag*scale; wave 1 = triangle-map table
// (tmap[t] = (ti<<8)|tj) so pair does a table lookup instead of sqrt+loops.
// ---------------------------------------------------------------------------
__global__ __launch_bounds__(256) void dep_prep(
    const float* __restrict__ z, const int* __restrict__ s,
    float* __restrict__ sq, float* __restrict__ sqmin,
    unsigned char* __restrict__ zb8, float* __restrict__ pvals,
    int* __restrict__ tmap, const float* __restrict__ norm,
    float* __restrict__ out, int N, int T)
{
    __shared__ float part[32][33];
    const int tid  = threadIdx.x;
    const int wave = tid >> 6, lane = tid & 63;
    const int half = lane >> 5, c = lane & 31;
    const int r0   = blockIdx.x * 32;

    if (blockIdx.x == 0 && wave == 1 && lane < T) {
        const int ti   = lane;
        const int base = ti * T - (ti * (ti - 1)) / 2;
        for (int tj = ti; tj < T; ++tj)
            tmap[base + (tj - ti)] = (ti << 8) | tj;
    }

    if (blockIdx.x == 0 && wave == 2) {
        int c0 = 0, c1 = 0, c2 = 0, c3 = 0;
        for (int it = lane; it < N / 4; it += 64) {
            int4 v = ((const int4*)s)[it];
            c0 += (v.x == 0) + (v.y == 0) + (v.z == 0) + (v.w == 0);
            c1 += (v.x == 1) + (v.y == 1) + (v.z == 1) + (v.w == 1);
            c2 += (v.x == 2) + (v.y == 2) + (v.z == 2) + (v.w == 2);
            c3 += (v.x == 3) + (v.y == 3) + (v.z == 3) + (v.w == 3);
        }
        #pragma unroll
        for (int off = 1; off < 64; off <<= 1) {
            c0 += __shfl_xor(c0, off, 64);
            c1 += __shfl_xor(c1, off, 64);
            c2 += __shfl_xor(c2, off, 64);
            c3 += __shfl_xor(c3, off, 64);
        }
        if (lane == 0) {
            const double n = (double)N;
            const double p0 = c0 / n, p1 = c1 / n, p2 = c2 / n, p3 = c3 / n;
            const double sump2 = p0*p0 + p1*p1 + p2*p2 + p3*p3;
            const double scale = (1.0 - exp(-1.0)) / ((double)norm[0] * n * n);
            pvals[0] = (float)p0; pvals[1] = (float)p1;
            pvals[2] = (float)p2; pvals[3] = (float)p3;
            pvals[4] = (float)sump2;
            pvals[5] = (float)scale;
            const double c2sum = (double)c0*c0 + (double)c1*c1
                               + (double)c2*c2 + (double)c3*c3;
            const double diag = n - c2sum / n;   // K_z[i,i] = 1 analytically
            out[0] = (float)(diag * scale);
        }
    }

    #pragma unroll
    for (int i = 0; i < 4; ++i) {
        const int rloc = wave * 8 + i * 2 + half;
        const int r    = r0 + rloc;
        float4 v = ((const float4*)z)[r * 32 + c];
        int pk = __builtin_amdgcn_cvt_pk_fp8_f32(v.x, v.y, 0, false);
        pk     = __builtin_amdgcn_cvt_pk_fp8_f32(v.z, v.w, pk, true);
        ((unsigned int*)zb8)[r * 32 + c] = (unsigned int)pk;
        part[rloc][c] = v.x*v.x + v.y*v.y + v.z*v.z + v.w*v.w;
    }
    __syncthreads();

    if (wave == 0 && lane < 32) {
        float sum = 0.f;
        #pragma unroll
        for (int k = 0; k < 32; ++k) sum += part[lane][k];   // conflict-free
        sq[r0 + lane] = sum;
        float mn = sum;
        #pragma unroll
        for (int off = 1; off < 32; off <<= 1)               // lanes 0..31
            mn = fminf(mn, __shfl_xor(mn, off, 64));
        if (lane == 0) sqmin[blockIdx.x] = mn;
    }
}

// ---------------------------------------------------------------------------
// Kernel B: persistent cross-tile DMA pipeline. 512 blocks (exactly 2/CU
// at 64KB LDS), grid-stride over 2080 tiles (~4 each). Double-buffered fp8
// panels: tile t+1's global_load_lds is issued into buf^1 BEFORE computing
// tile t, so the single per-tile __syncthreads finds vmcnt already drained
// (kills R9's per-block cold-drain serialization). No register prefetch
// (R4 spill), no in-loop serial stage-drain (R8), no fences (R3).
// Same verified global-side XOR swizzle + fp8 MFMA + bound epilogue as R9.
// ---------------------------------------------------------------------------
__global__ __launch_bounds__(256, 2) void dep_pair(
    const unsigned char* __restrict__ zb8, const float* __restrict__ sq,
    const float* __restrict__ sqmin, const int* __restrict__ s,
    const float* __restrict__ pvals, const int* __restrict__ tmap,
    float* __restrict__ out, int NT)
{
    __shared__ unsigned char pan[2][2][BT * ZD];   // [buf][A/B], 64KB

    const int tid  = threadIdx.x;
    const int wave = tid >> 6, lane = tid & 63;
    const int wi   = wave >> 1, wj = wave & 1;
    const int l15  = lane & 15, quad = lane >> 4;
    const int rl   = lane >> 3, cch = lane & 7;
    const int gch  = cch ^ rl;           // global-side swizzle (row&7 == rl)

    int t = blockIdx.x;
    if (t >= NT) return;

    int mt = tmap[t];
    int ti = mt >> 8, tj = mt & 255;

    // stage tile (ti,tj) panels into buffer `buf`: 4+4 DMAs of 1KB per wave
    auto stage = [&](int sti, int stj, int buf) {
        const unsigned char* gA = zb8 + (size_t)sti * BT * ZD;
        const unsigned char* gB = zb8 + (size_t)stj * BT * ZD;
        #pragma unroll
        for (int k = 0; k < 4; ++k) {
            const int r0i = (wave * 4 + k) * 8;            // wave-uniform
            const size_t go = (size_t)(r0i + rl) * ZD + (gch << 4);
            async_copy16(gA + go, &pan[buf][0][r0i * ZD]);
            async_copy16(gB + go, &pan[buf][1][r0i * ZD]);
        }
    };

    stage(ti, tj, 0);
    __syncthreads();                     // only cold drain of the pipeline
    int p = 0;

    while (true) {
        // issue NEXT tile's DMA first; it drains during compute below
        const int tn = t + gridDim.x;
        const bool have = (tn < NT);
        int nti = 0, ntj = 0;
        if (have) {
            const int m2 = tmap[tn];
            nti = m2 >> 8; ntj = m2 & 255;
            stage(nti, ntj, p ^ 1);
        }

        const int i0 = ti * BT, j0 = tj * BT;
        const unsigned char* Apan = &pan[p][0][0];
        const unsigned char* Bpan = &pan[p][1][0];

        f32x4 accv[4][4];
        #pragma unroll
        for (int a = 0; a < 4; ++a)
            #pragma unroll
            for (int b = 0; b < 4; ++b)
                accv[a][b] = (f32x4){0.f, 0.f, 0.f, 0.f};

        const int sub = (quad & 1) * 8;      // 8B half within 16B chunk
        #pragma unroll
        for (int kc = 0; kc < 4; ++kc) {
            long af[4], bfr[4];
            const int ch = (kc * 2 + (quad >> 1)) ^ (l15 & 7);
            #pragma unroll
            for (int it = 0; it < 4; ++it) {
                const int row = wi * 64 + it * 16 + l15;
                af[it] = *(const long*)(Apan + row * ZD + (ch << 4) + sub);
            }
            #pragma unroll
            for (int jt = 0; jt < 4; ++jt) {
                const int row = wj * 64 + jt * 16 + l15;
                bfr[jt] = *(const long*)(Bpan + row * ZD + (ch << 4) + sub);
            }
            #pragma unroll
            for (int it = 0; it < 4; ++it)
                #pragma unroll
                for (int jt = 0; jt < 4; ++jt)
                    accv[it][jt] = __builtin_amdgcn_mfma_f32_16x16x32_fp8_fp8(
                        af[it], bfr[jt], accv[it][jt], 0, 0, 0);
        }

        // ---- epilogue: wave-max of dots vs conservative d2 lower bound ----
        float m = -1e30f;
        #pragma unroll
        for (int it = 0; it < 4; ++it)
            #pragma unroll
            for (int jt = 0; jt < 4; ++jt) {
                const f32x4 v = accv[it][jt];
                m = fmaxf(m, fmaxf(fmaxf(v[0], v[1]), fmaxf(v[2], v[3])));
            }
        #pragma unroll
        for (int off = 1; off < 64; off <<= 1)
            m = fmaxf(m, __shfl_xor(m, off, 64));

        const int gA = (i0 >> 5) + wi * 2;    // 32-row sqmin groups
        const int gB = (j0 >> 5) + wj * 2;
        const float sminA = fminf(sqmin[gA], sqmin[gA + 1]);
        const float sminB = fminf(sqmin[gB], sqmin[gB + 1]);
        const float bound = sminA + sminB - 2.0f * m;

        if (bound < D2_TRIG) {   // wave-uniform; diag quadrants + rare
            const float p0 = pvals[0], p1 = pvals[1],
                        p2 = pvals[2], p3 = pvals[3];
            const float sump2 = pvals[4], scale = pvals[5];
            const float pr[4] = {p0, p1, p2, p3};

            const int ibase = i0 + wi * 64, jbase = j0 + wj * 64;
            float sqj[4];
            #pragma unroll
            for (int jt = 0; jt < 4; ++jt)
                sqj[jt] = sq[jbase + jt * 16 + l15];

            float local = 0.f;
            #pragma unroll
            for (int it = 0; it < 4; ++it) {
                #pragma unroll
                for (int r = 0; r < 4; ++r) {
                    const int i = ibase + it * 16 + quad * 4 + r;  // C/D row
                    const float sqi = sq[i];
                    #pragma unroll
                    for (int jt = 0; jt < 4; ++jt) {
                        const int j = jbase + jt * 16 + l15;       // C/D col
                        float d2 = sqi + sqj[jt] - 2.0f * accv[it][jt][r];
                        d2 = fmaxf(d2, 0.0f);
                        if (d2 < D2_CUT && i != j) {
                            const int si = s[i], sj = s[j];
                            const float w = (si == sj ? 1.0f : 0.0f)
                                          - pr[si] - pr[sj] + sump2;
                            local += w * __expf(-0.5f * d2);
                        }
                    }
                }
            }
            if (ti < tj) local *= 2.0f;   // off-diag tiles count both orders

            #pragma unroll
            for (int off = 32; off > 0; off >>= 1)
                local += __shfl_down(local, off, 64);
            if (lane == 0 && local != 0.0f)
                atomicAdd(out, local * scale);
        }

        __syncthreads();   // drains next tile's DMA + guards buf reuse
        if (!have) break;
        t = tn; ti = nti; tj = ntj; p ^= 1;
    }
}

extern "C" void kernel_launch(void* const* d_in, const int* in_sizes, int n_in,
                              void* d_out, int out_size, void* d_ws, size_t ws_size,
                              hipStream_t stream)
{
    const float* z    = (const float*)d_in[0];
    const int*   s    = (const int*)d_in[1];
    const float* norm = (const float*)d_in[2];
    float* out = (float*)d_out;

    const int N  = in_sizes[1];      // 8192
    const int T  = N / BT;           // 64
    const int NT = T * (T + 1) / 2;  // 2080

    char* ws = (char*)d_ws;
    float*         pvals = (float*)ws;                            // @0, 64B
    float*         sq    = (float*)(ws + 64);                     // N floats
    float*         sqmin = (float*)(ws + 64 + (size_t)N * 4);     // N/32
    int*           tmap  = (int*)(ws + 64 + (size_t)N * 4
                                  + (size_t)(N / 32) * 4);        // NT ints
    unsigned char* zb8   = (unsigned char*)(ws + 64 + (size_t)N * 4
                                  + (size_t)(N / 32) * 4
                                  + (((size_t)NT * 4 + 63) & ~63ull));

    dep_prep<<<N / 32, 256, 0, stream>>>(z, s, sq, sqmin, zb8, pvals, tmap,
                                         norm, out, N, T);
    dep_pair<<<512, 256, 0, stream>>>(zb8, sq, sqmin, s, pvals, tmap,
                                      out, NT);
}

// Round 11
// 77.653 us; speedup vs baseline: 1.0428x; 1.0428x over previous
//
#include <hip/hip_runtime.h>
#include <hip/hip_bf16.h>

typedef float f32x4 __attribute__((ext_vector_type(4)));

#define ZD      128      // feature dim (bytes per fp8 row, too)
#define BT      128      // block tile (128x128, 64x64 per wave)
#define D2_CUT  60.0f    // exact-path cutoff: exp(-30)~9e-14
#define D2_TRIG 70.0f    // trigger: fp8 dot err <= ~+-3 on d2 => skip implies
                         // true d2 >= 70-6 > D2_CUT (12-sigma data margin)

// async global->LDS DMA, 16B per lane; LDS dest = wave-uniform base + lane*16
__device__ __forceinline__ void async_copy16(const unsigned char* g,
                                             unsigned char* l) {
    __builtin_amdgcn_global_load_lds(
        (const __attribute__((address_space(1))) unsigned int*)g,
        (__attribute__((address_space(3))) unsigned int*)l,
        16, 0, 0);
}

// ---------------------------------------------------------------------------
// Kernel A: 256 blocks x 32 rows. ||z_i||^2 (fp32 exact), per-32-row min,
// z -> fp8 e4m3 (HW cvt_pk, 4 elems/lane/row). Block 0 / wave 2: class
// counts over all s, analytic diagonal, out[0] = diag*scale.
// ---------------------------------------------------------------------------
__global__ __launch_bounds__(256) void dep_prep(
    const float* __restrict__ z, const int* __restrict__ s,
    float* __restrict__ sq, float* __restrict__ sqmin,
    unsigned char* __restrict__ zb8, float* __restrict__ pvals,
    const float* __restrict__ norm, float* __restrict__ out, int N)
{
    __shared__ float part[32][33];
    const int tid  = threadIdx.x;
    const int wave = tid >> 6, lane = tid & 63;
    const int half = lane >> 5, c = lane & 31;
    const int r0   = blockIdx.x * 32;

    if (blockIdx.x == 0 && wave == 2) {
        int c0 = 0, c1 = 0, c2 = 0, c3 = 0;
        for (int it = lane; it < N / 4; it += 64) {
            int4 v = ((const int4*)s)[it];
            c0 += (v.x == 0) + (v.y == 0) + (v.z == 0) + (v.w == 0);
            c1 += (v.x == 1) + (v.y == 1) + (v.z == 1) + (v.w == 1);
            c2 += (v.x == 2) + (v.y == 2) + (v.z == 2) + (v.w == 2);
            c3 += (v.x == 3) + (v.y == 3) + (v.z == 3) + (v.w == 3);
        }
        #pragma unroll
        for (int off = 1; off < 64; off <<= 1) {
            c0 += __shfl_xor(c0, off, 64);
            c1 += __shfl_xor(c1, off, 64);
            c2 += __shfl_xor(c2, off, 64);
            c3 += __shfl_xor(c3, off, 64);
        }
        if (lane == 0) {
            const double n = (double)N;
            const double p0 = c0 / n, p1 = c1 / n, p2 = c2 / n, p3 = c3 / n;
            const double sump2 = p0*p0 + p1*p1 + p2*p2 + p3*p3;
            const double scale = (1.0 - exp(-1.0)) / ((double)norm[0] * n * n);
            pvals[0] = (float)p0; pvals[1] = (float)p1;
            pvals[2] = (float)p2; pvals[3] = (float)p3;
            pvals[4] = (float)sump2;
            pvals[5] = (float)scale;
            const double c2sum = (double)c0*c0 + (double)c1*c1
                               + (double)c2*c2 + (double)c3*c3;
            const double diag = n - c2sum / n;   // K_z[i,i] = 1 analytically
            out[0] = (float)(diag * scale);
        }
    }

    #pragma unroll
    for (int i = 0; i < 4; ++i) {
        const int rloc = wave * 8 + i * 2 + half;
        const int r    = r0 + rloc;
        float4 v = ((const float4*)z)[r * 32 + c];
        int pk = __builtin_amdgcn_cvt_pk_fp8_f32(v.x, v.y, 0, false);
        pk     = __builtin_amdgcn_cvt_pk_fp8_f32(v.z, v.w, pk, true);
        ((unsigned int*)zb8)[r * 32 + c] = (unsigned int)pk;
        part[rloc][c] = v.x*v.x + v.y*v.y + v.z*v.z + v.w*v.w;
    }
    __syncthreads();

    if (wave == 0 && lane < 32) {
        float sum = 0.f;
        #pragma unroll
        for (int k = 0; k < 32; ++k) sum += part[lane][k];   // conflict-free
        sq[r0 + lane] = sum;
        float mn = sum;
        #pragma unroll
        for (int off = 1; off < 32; off <<= 1)               // lanes 0..31
            mn = fminf(mn, __shfl_xor(mn, off, 64));
        if (lane == 0) sqmin[blockIdx.x] = mn;
    }
}

// ---------------------------------------------------------------------------
// Kernel B: one block per 128x128 upper-triangle tile (2080 blocks) — the
// measured-best R9 configuration. fp8 A+B panels = 32KB LDS -> 4 blocks/CU
// (16 waves/CU): each block's DMA drain is covered by 3 co-resident blocks'
// compute (implicit wave-level overlap; explicit dbuf at 2/CU measured
// WORSE, R10). Async global_load_lds staging with global-side XOR swizzle
// at 16B-chunk granularity (ch ^= row&7); fragment ds_read_b64 4-way
// bank-aliased (1.58x, acceptable). mfma_f32_16x16x32_fp8_fp8, same
// lane->element mapping as bf16 (8 elems/lane), 1 byte/elem.
// Epilogue: conservative d2 lower bound (TRIG widened for fp8 dot err);
// rare exact path adds local*scale onto out[0] (pre-set to diag*scale).
// ---------------------------------------------------------------------------
__global__ __launch_bounds__(256, 4) void dep_pair(
    const unsigned char* __restrict__ zb8, const float* __restrict__ sq,
    const float* __restrict__ sqmin, const int* __restrict__ s,
    const float* __restrict__ pvals, float* __restrict__ out, int T)
{
    __shared__ unsigned char Apan[BT * ZD];   // 16KB
    __shared__ unsigned char Bpan[BT * ZD];   // 16KB

    const int tid  = threadIdx.x;
    const int wave = tid >> 6, lane = tid & 63;

    // block-uniform triangle map t -> (ti <= tj)
    const int t = blockIdx.x;
    #define TRI_BASE(x) ((x) * T - ((x) * ((x) - 1)) / 2)
    double disc = (2.0 * T + 1.0) * (2.0 * T + 1.0) - 8.0 * (double)t;
    int ti = (int)((2.0 * T + 1.0 - sqrt(disc)) * 0.5);
    if (ti < 0) ti = 0;
    if (ti > T - 1) ti = T - 1;
    while (ti + 1 < T && TRI_BASE(ti + 1) <= t) ++ti;
    while (ti > 0 && TRI_BASE(ti) > t) --ti;
    const int tj = ti + (t - TRI_BASE(ti));
    #undef TRI_BASE

    const int i0 = ti * BT, j0 = tj * BT;
    const int wi = wave >> 1, wj = wave & 1;
    const int l15 = lane & 15, quad = lane >> 4;

    // async stage both panels: per wave 4+4 DMAs of 1KB (8 rows each).
    // LDS[row][c] = G[row][c ^ (row&7)]  (global-side swizzle; base uniform)
    {
        const unsigned char* gAp = zb8 + (size_t)i0 * ZD;
        const unsigned char* gBp = zb8 + (size_t)j0 * ZD;
        const int rl  = lane >> 3;          // row within 8-row group (0..7)
        const int cch = lane & 7;           // dest 16B-chunk within row
        const int gch = cch ^ rl;           // source chunk (row&7 == rl)
        #pragma unroll
        for (int k = 0; k < 4; ++k) {
            const int r0i = (wave * 4 + k) * 8;        // wave-uniform
            const size_t go = (size_t)(r0i + rl) * ZD + (gch << 4);
            async_copy16(gAp + go, Apan + r0i * ZD);
            async_copy16(gBp + go, Bpan + r0i * ZD);
        }
    }
    __syncthreads();   // vmcnt(0) drain; 3 co-resident blocks overlap

    f32x4 accv[4][4];
    #pragma unroll
    for (int a = 0; a < 4; ++a)
        #pragma unroll
        for (int b = 0; b < 4; ++b)
            accv[a][b] = (f32x4){0.f, 0.f, 0.f, 0.f};

    const int sub = (quad & 1) * 8;         // 8B half within 16B chunk
    #pragma unroll
    for (int kc = 0; kc < 4; ++kc) {
        long af[4], bfr[4];
        // orig chunk = kc*2 + quad/2; row&7 == l15&7 for all fragment rows
        const int ch = (kc * 2 + (quad >> 1)) ^ (l15 & 7);
        #pragma unroll
        for (int it = 0; it < 4; ++it) {
            const int row = wi * 64 + it * 16 + l15;
            af[it] = *(const long*)(Apan + row * ZD + (ch << 4) + sub);
        }
        #pragma unroll
        for (int jt = 0; jt < 4; ++jt) {
            const int row = wj * 64 + jt * 16 + l15;
            bfr[jt] = *(const long*)(Bpan + row * ZD + (ch << 4) + sub);
        }
        #pragma unroll
        for (int it = 0; it < 4; ++it)
            #pragma unroll
            for (int jt = 0; jt < 4; ++jt)
                accv[it][jt] = __builtin_amdgcn_mfma_f32_16x16x32_fp8_fp8(
                    af[it], bfr[jt], accv[it][jt], 0, 0, 0);
    }

    // ---- fast epilogue: wave-max of dots vs conservative d2 lower bound ----
    float m = -1e30f;
    #pragma unroll
    for (int it = 0; it < 4; ++it)
        #pragma unroll
        for (int jt = 0; jt < 4; ++jt) {
            const f32x4 v = accv[it][jt];
            m = fmaxf(m, fmaxf(fmaxf(v[0], v[1]), fmaxf(v[2], v[3])));
        }
    #pragma unroll
    for (int off = 1; off < 64; off <<= 1)
        m = fmaxf(m, __shfl_xor(m, off, 64));

    const int gA = (i0 >> 5) + wi * 2;        // 32-row sqmin groups
    const int gB = (j0 >> 5) + wj * 2;
    const float sminA = fminf(sqmin[gA], sqmin[gA + 1]);
    const float sminB = fminf(sqmin[gB], sqmin[gB + 1]);
    const float bound = sminA + sminB - 2.0f * m;

    if (bound < D2_TRIG) {   // wave-uniform; diag quadrants + rare triggers
        const float p0 = pvals[0], p1 = pvals[1],
                    p2 = pvals[2], p3 = pvals[3];
        const float sump2 = pvals[4], scale = pvals[5];
        const float p[4] = {p0, p1, p2, p3};

        const int ibase = i0 + wi * 64, jbase = j0 + wj * 64;
        float sqj[4];
        #pragma unroll
        for (int jt = 0; jt < 4; ++jt) sqj[jt] = sq[jbase + jt * 16 + l15];

        float local = 0.f;
        #pragma unroll
        for (int it = 0; it < 4; ++it) {
            #pragma unroll
            for (int r = 0; r < 4; ++r) {
                const int i = ibase + it * 16 + quad * 4 + r;  // C/D row
                const float sqi = sq[i];
                #pragma unroll
                for (int jt = 0; jt < 4; ++jt) {
                    const int j = jbase + jt * 16 + l15;       // C/D col
                    float d2 = sqi + sqj[jt] - 2.0f * accv[it][jt][r];
                    d2 = fmaxf(d2, 0.0f);
                    if (d2 < D2_CUT && i != j) {
                        const int si = s[i], sj = s[j];
                        const float w = (si == sj ? 1.0f : 0.0f)
                                      - p[si] - p[sj] + sump2;
                        local += w * __expf(-0.5f * d2);
                    }
                }
            }
        }
        if (ti < tj) local *= 2.0f;   // off-diag tiles count both orders

        #pragma unroll
        for (int off = 32; off > 0; off >>= 1)
            local += __shfl_down(local, off, 64);
        if (lane == 0 && local != 0.0f)
            atomicAdd(out, local * scale);
    }
}

extern "C" void kernel_launch(void* const* d_in, const int* in_sizes, int n_in,
                              void* d_out, int out_size, void* d_ws, size_t ws_size,
                              hipStream_t stream)
{
    const float* z    = (const float*)d_in[0];
    const int*   s    = (const int*)d_in[1];
    const float* norm = (const float*)d_in[2];
    float* out = (float*)d_out;

    const int N = in_sizes[1];       // 8192
    const int T = N / BT;            // 64

    char* ws = (char*)d_ws;
    float*         pvals = (float*)ws;                        // 6 floats @0
    float*         sq    = (float*)(ws + 64);                 // N floats
    float*         sqmin = (float*)(ws + 64 + (size_t)N * 4); // N/32
    unsigned char* zb8   = (unsigned char*)(ws + 64 + (size_t)N * 4
                                            + (size_t)(N / 32) * 4); // 16B-aligned

    dep_prep<<<N / 32, 256, 0, stream>>>(z, s, sq, sqmin, zb8, pvals,
                                         norm, out, N);
    const int nblocks = T * (T + 1) / 2;   // 2080
    dep_pair<<<nblocks, 256, 0, stream>>>(zb8, sq, sqmin, s, pvals, out, T);
}